// Round 13
// baseline (23.187 us; speedup 1.0000x reference)
//
#include <hip/hip_runtime.h>
#include <hip/hip_bf16.h>
#include <math.h>

// Problem constants (from reference)
#define V_SZ 500000
#define E_SZ 128
#define H_SZ 128
#define L_SZ 10
#define P_SZ 10
#define N_SZ 50
#define NSEQ (P_SZ + N_SZ)       // 60 non-phrase sequences
#define NBLK 60                  // block j handles (seq 0, seq j+1)
#define TPB  384                 // 6 waves; wave w owns gate rows [64w, 64w+64)

#define FLAG_STRIDE 16
#define SLOT_STRIDE 16
#define FLAG_MAGIC  0x9E370000u

#define GI_STR 388               // gi_all row stride (floats): 16B-aligned, ~2-way banks
#define XS_STR 136               // xs_bf16 row stride (bf16): 272B, 16B-aligned
#define SLAB_ROWS 192            // weight staging slab (48 KB bf16)

typedef __attribute__((ext_vector_type(8))) short bf16x8;  // 8 bf16 = 4 VGPRs (MFMA A/B frag)
typedef __attribute__((ext_vector_type(4))) float f32x4;   // MFMA C/D frag

#define MFMA(a, b, c) __builtin_amdgcn_mfma_f32_16x16x32_bf16((a), (b), (c), 0, 0, 0)

__device__ __forceinline__ float sigmoidf(float x) {
    return 1.0f / (1.0f + expf(-x));
}

__device__ __forceinline__ unsigned short f2bf(float f) {   // RNE f32 -> bf16
    unsigned u = __float_as_uint(f);
    u += 0x7FFFu + ((u >> 16) & 1u);
    return (unsigned short)(u >> 16);
}

// Block j processes TWO sequences through the same MFMAs:
//   B-column parity 0 = sequence 0 (recomputed identically by every block),
//   B-column parity 1 = sequence j+1.
// Weights are staged global->LDS coalesced (XOR-swizzled), then read as
// fragments via ds_read_b128 — removes the 32-64 lines/instruction scatter
// of direct fragment loads (round-11 theory).
__global__ __launch_bounds__(TPB) void gru_fused(
    const int*   __restrict__ phr_inds,
    const int*   __restrict__ pos_inds,
    const int*   __restrict__ neg_inds,
    const float* __restrict__ u_emb,
    const float* __restrict__ v_emb,
    const float* __restrict__ w_ih,
    const float* __restrict__ w_hh,
    const float* __restrict__ b_ih,
    const float* __restrict__ b_hh,
    const float* __restrict__ h0,
    float*       __restrict__ slots,    // [NBLK*SLOT_STRIDE] workspace (s scalars)
    unsigned*    __restrict__ flags,    // [NBLK*FLAG_STRIDE] workspace
    float*       __restrict__ out)      // f32 scalar
{
    __shared__ __align__(16) unsigned short stage[SLAB_ROWS * E_SZ];  // 48 KB weight slab
    __shared__ __align__(16) unsigned short xs_bf16[2][16 * XS_STR];  // x^T per seq-group
    __shared__ __align__(16) float          gi_all[2][16 * GI_STR];   // gi[seq][col=l][row=g]
    __shared__ __align__(16) float          gh_s[2][3 * H_SZ];        // gh exchange per seq
    __shared__ __align__(16) unsigned short hs_bf16[2][H_SZ];         // h broadcast per seq
    __shared__ __align__(16) float          node[2][H_SZ];            // final h (f32) per seq

    const int bj   = blockIdx.x;             // 0..59
    const int seqB = bj + 1;                 // enc row this block owns (1..60)
    const int t    = threadIdx.x;
    const int lane = t & 63;
    const int wv   = t >> 6;                 // wave 0..5
    const int kg   = lane >> 4;              // k-group 0..3
    const int col  = lane & 15;              // B/D column for this lane
    const int arow = wv * 64 + col;          // A row (lane&15 = row within 16-block)

    // ---- gather x rows for BOTH sequences (deepest-latency loads first) ----
    for (int i = t; i < 2 * L_SZ * 32; i += TPB) {
        const int r  = i >> 5;               // 0..19
        const int e4 = i & 31;
        const int g  = (r < L_SZ) ? 0 : 1;
        const int l  = (r < L_SZ) ? r : r - L_SZ;
        int idx; const float* emb;
        if (g == 0)             { idx = phr_inds[l];                       emb = u_emb; }
        else if (seqB <= P_SZ)  { idx = pos_inds[(seqB - 1) * L_SZ + l];   emb = v_emb; }
        else                    { idx = neg_inds[(seqB - 1 - P_SZ) * L_SZ + l]; emb = v_emb; }
        const float4 v = *reinterpret_cast<const float4*>(emb + (size_t)idx * E_SZ + e4 * 4);
        short4 s4;
        s4.x = (short)f2bf(v.x); s4.y = (short)f2bf(v.y);
        s4.z = (short)f2bf(v.z); s4.w = (short)f2bf(v.w);
        *reinterpret_cast<short4*>((char*)&xs_bf16[g][0] + l * (XS_STR * 2) + e4 * 8) = s4;
    }
    // (cols 10..15 of each group left uninitialized: their gi outputs are never read)

    // ---- biases + h0 early (latency overlap; writes read only after barriers) ----
    const int gseq = t >> 7;                 // 0 or 1 (for t<256)
    const int gu   = t & 127;
    float bih_r = 0.f, bih_z = 0.f, bih_n = 0.f;
    float bhh_r = 0.f, bhh_z = 0.f, bhh_n = 0.f;
    float h_reg = 0.f;
    if (t < 2 * H_SZ) {
        bih_r = b_ih[gu]; bih_z = b_ih[gu + 128]; bih_n = b_ih[gu + 256];
        bhh_r = b_hh[gu]; bhh_z = b_hh[gu + 128]; bhh_n = b_hh[gu + 256];
        h_reg = h0[gu];
        hs_bf16[gseq][gu] = f2bf(h_reg);     // both groups init to h0
    }

    // ---- weights: coalesced global -> swizzled LDS slab -> register fragments ----
    bf16x8 aih[4][4], ahh[4][4];
    #pragma unroll
    for (int m = 0; m < 2; ++m) {
        const float* W = (m == 0) ? w_ih : w_hh;
        #pragma unroll
        for (int s = 0; s < 2; ++s) {
            // load 192 rows x 128 f32, fully coalesced (consecutive lanes -> consecutive 16B)
            #pragma unroll 8
            for (int q = 0; q < (SLAB_ROWS * E_SZ / 4) / TPB; ++q) {   // 16 iters
                const int fi = q * TPB + t;          // float4 index in slab
                const int lr = fi >> 5;              // local row 0..191
                const int e4 = fi & 31;
                const float4 v = *reinterpret_cast<const float4*>(
                    W + (size_t)(s * SLAB_ROWS + lr) * E_SZ + e4 * 4);
                short4 s4;
                s4.x = (short)f2bf(v.x); s4.y = (short)f2bf(v.y);
                s4.z = (short)f2bf(v.z); s4.w = (short)f2bf(v.w);
                const int byte = (lr * 256 + e4 * 8) ^ ((lr & 7) << 4);  // G4 XOR-swizzle
                *reinterpret_cast<short4*>((char*)stage + byte) = s4;
            }
            __syncthreads();                          // slab visible (also covers xs/hs writes)

            if (wv >= s * 3 && wv < (s + 1) * 3) {    // waves whose rows live in this slab
                const int lr0 = arow - s * SLAB_ROWS;
                #pragma unroll
                for (int mb = 0; mb < 4; ++mb) {
                    #pragma unroll
                    for (int kb = 0; kb < 4; ++kb) {
                        const int lr   = lr0 + mb * 16;
                        const int byte = (lr * 256 + kb * 64 + kg * 16) ^ ((lr & 7) << 4);
                        const bf16x8 f = *reinterpret_cast<const bf16x8*>((const char*)stage + byte);
                        if (m == 0) aih[mb][kb] = f;
                        else        ahh[mb][kb] = f;
                    }
                }
            }
            __syncthreads();                          // all reads done before slab overwrite
        }
    }
    // (last staging barrier also made xs_bf16 / hs_bf16 visible to everyone)

    // ---- gi = W_ih @ X^T, one MFMA pass per sequence group ----
    #pragma unroll
    for (int g = 0; g < 2; ++g) {
        f32x4 g0 = {0.f,0.f,0.f,0.f}, g1 = {0.f,0.f,0.f,0.f};
        f32x4 g2 = {0.f,0.f,0.f,0.f}, g3 = {0.f,0.f,0.f,0.f};
        #pragma unroll
        for (int kb = 0; kb < 4; ++kb) {
            const bf16x8 xb = *reinterpret_cast<const bf16x8*>(
                (const char*)&xs_bf16[g][0] + col * (XS_STR * 2) + kb * 64 + kg * 16);
            g0 = MFMA(aih[0][kb], xb, g0);
            g1 = MFMA(aih[1][kb], xb, g1);
            g2 = MFMA(aih[2][kb], xb, g2);
            g3 = MFMA(aih[3][kb], xb, g3);
        }
        const int rb = wv * 64 + kg * 4;     // D row base: (lane>>4)*4 + reg (m89-verified)
        *reinterpret_cast<f32x4*>(&gi_all[g][col * GI_STR + rb     ]) = g0;
        *reinterpret_cast<f32x4*>(&gi_all[g][col * GI_STR + rb + 16]) = g1;
        *reinterpret_cast<f32x4*>(&gi_all[g][col * GI_STR + rb + 32]) = g2;
        *reinterpret_cast<f32x4*>(&gi_all[g][col * GI_STR + rb + 48]) = g3;
    }
    // no barrier needed: step-0 barrier [A] orders gi_all writes before gate reads

    // ---- recurrent steps: 16 MFMA/wave/step, cols alternate seq0/seqB ----
    for (int l = 0; l < L_SZ; ++l) {
        f32x4 a0 = {0.f,0.f,0.f,0.f}, a1 = {0.f,0.f,0.f,0.f};
        f32x4 a2 = {0.f,0.f,0.f,0.f}, a3 = {0.f,0.f,0.f,0.f};
        #pragma unroll
        for (int kb = 0; kb < 4; ++kb) {
            // col parity selects which sequence's h this column multiplies
            const bf16x8 bh = *reinterpret_cast<const bf16x8*>(
                (const char*)&hs_bf16[col & 1][0] + kb * 64 + kg * 16);
            a0 = MFMA(ahh[0][kb], bh, a0);
            a1 = MFMA(ahh[1][kb], bh, a1);
            a2 = MFMA(ahh[2][kb], bh, a2);
            a3 = MFMA(ahh[3][kb], bh, a3);
        }
        if (col < 2) {                        // cols 0,1 hold gh for seq0 / seqB
            const int rb = wv * 64 + kg * 4;
            *reinterpret_cast<f32x4*>(&gh_s[col][rb     ]) = a0;
            *reinterpret_cast<f32x4*>(&gh_s[col][rb + 16]) = a1;
            *reinterpret_cast<f32x4*>(&gh_s[col][rb + 32]) = a2;
            *reinterpret_cast<f32x4*>(&gh_s[col][rb + 48]) = a3;
        }
        __syncthreads();                      // [A] gh_s (and, at l==0, gi_all) visible

        if (t < 2 * H_SZ) {
            const float* gi = &gi_all[gseq][l * GI_STR];
            const float* gh = &gh_s[gseq][0];
            const float r = sigmoidf(gi[gu      ] + bih_r + (gh[gu      ] + bhh_r));
            const float z = sigmoidf(gi[gu + 128] + bih_z + (gh[gu + 128] + bhh_z));
            const float n = tanhf  (gi[gu + 256] + bih_n + r * (gh[gu + 256] + bhh_n));
            h_reg = (1.0f - z) * n + z * h_reg;
            if (l < L_SZ - 1) hs_bf16[gseq][gu] = f2bf(h_reg);  // re-broadcast
            else              node[gseq][gu]   = h_reg;         // final h (f32)
        }
        __syncthreads();                      // [B] hs_bf16 / node visible
    }

    // ---- local dot: s = (node0 . node1) / 128, computed by wave 0 ----
    if (t >= 64) return;                      // no further barriers below

    float d = node[0][t] * node[1][t] + node[0][t + 64] * node[1][t + 64];
    #pragma unroll
    for (int off = 32; off > 0; off >>= 1) d += __shfl_down(d, off);
    const float s_own = d * (1.0f / (float)H_SZ);   // valid in lane 0

    // ---- publish (blocks 1..59) / aggregate (block 0) ----
    if (bj != 0) {
        if (t == 0) {
            slots[bj * SLOT_STRIDE] = s_own;   // plain store, bit-deterministic
            __threadfence();                   // release: slot visible before flag
            atomicExch(&flags[bj * FLAG_STRIDE], FLAG_MAGIC + (unsigned)bj);
        }
        return;
    }

    // block 0: lane k owns enc-row k+1. Lane 0 = own s; lanes 1..59 = block k's.
    float sv = 0.0f;
    if (t == 0) sv = s_own;
    else if (t < NSEQ) {
        const unsigned want = FLAG_MAGIC + (unsigned)t;
        while (atomicAdd(&flags[t * FLAG_STRIDE], 0u) != want) {
            __builtin_amdgcn_s_sleep(2);
        }
        __threadfence();                       // acquire: order slot read after flag
        sv = slots[t * SLOT_STRIDE];
    }

    float vp = 0.0f, vn = 0.0f;
    if (t < P_SZ)      vp = sv;                              // rows 1..10: pos
    else if (t < NSEQ) vn = (sv > 0.0f) ? expf(sv) : 0.0f;   // rows 11..60: neg

    #pragma unroll
    for (int off = 32; off > 0; off >>= 1) {
        vp += __shfl_down(vp, off);
        vn += __shfl_down(vn, off);
    }
    if (t == 0) {
        out[0] = logf(1.0f + vn) - vp;   // -(neg_loss + pos_loss)
    }
}

extern "C" void kernel_launch(void* const* d_in, const int* in_sizes, int n_in,
                              void* d_out, int out_size, void* d_ws, size_t ws_size,
                              hipStream_t stream) {
    const int*   phr_inds = (const int*)  d_in[0];
    const int*   pos_inds = (const int*)  d_in[1];
    const int*   neg_inds = (const int*)  d_in[2];
    const float* u_emb    = (const float*)d_in[3];
    const float* v_emb    = (const float*)d_in[4];
    const float* w_ih     = (const float*)d_in[5];
    const float* w_hh     = (const float*)d_in[6];
    const float* b_ih     = (const float*)d_in[7];
    const float* b_hh     = (const float*)d_in[8];
    const float* h0       = (const float*)d_in[9];

    float*    slots = (float*)d_ws;                       // s scalars (strided)
    unsigned* flags = (unsigned*)((char*)d_ws + 16384);   // separate region

    gru_fused<<<NBLK, TPB, 0, stream>>>(phr_inds, pos_inds, neg_inds,
                                        u_emb, v_emb, w_ih, w_hh, b_ih, b_hh, h0,
                                        slots, flags, (float*)d_out);
}